// Round 8
// baseline (1815.083 us; speedup 1.0000x reference)
//
#include <hip/hip_runtime.h>

// MEASUREMENT ROUND: R0 structure + internal x64 repetition.
// Purpose: (1) make this kernel the longest dispatch so rocprof's top-5
// finally shows OUR counters (FETCH_SIZE, VALUBusy, Occupancy);
// (2) slope (dur - 54.6)/63 = warm-pass cost, separating DRAM-side cost
// from execution-side cost. Output identical to R0 (written once).
#define PP 32
#define SS 4
#define CC 64
#define HH 128
#define WW 128
#define NC 32
#define OO 32
#define REPS 64

__global__ __launch_bounds__(256) void probe_kernel(
    const float* __restrict__ input,     // [P,S,C,H,W]
    const int*   __restrict__ size_raw,  // [P]
    const int*   __restrict__ pix,       // [P]
    const int*   __restrict__ channels,  // [P,NC]
    float*       __restrict__ out)       // [P,S,NC,O,O]
{
    const int idx = blockIdx.x * 256 + threadIdx.x;

    const int q = idx & (OO - 1);
    const int o = (idx >> 5) & (OO - 1);
    const int c = (idx >> 10) & (NC - 1);
    const int s = (idx >> 15) & (SS - 1);
    const int p = idx >> 17;

    const int size = size_raw[p] + OO;          // [32,128]
    const int wr = WW - size + 1;
    const int hr = HH - size + 1;
    const int pm = pix[p] % (wr * hr);
    const int offy = pm / wr;
    const int offx = pm - offy * wr;
    const int ch = channels[p * NC + c];

    const int sy = offy + ((o * size) >> 5);
    const int ey = offy + (((o + 1) * size + 31) >> 5);
    const int sx = offx + ((q * size) >> 5);
    const int ex = offx + (((q + 1) * size + 31) >> 5);

    const float* base = input + ((size_t)((p * SS + s) * CC + ch)) * (HH * WW);
    const float rcnt = __builtin_amdgcn_rcpf((float)((ey - sy) * (ex - sx)));

    float sink = 0.0f;
    #pragma unroll 1
    for (int r = 0; r < REPS; ++r) {
        int off = 0;
        asm volatile("" : "+v"(off));   // opaque zero: loads can't CSE across reps
        const float* b = base + off;
        float acc = 0.0f;
        for (int y = sy; y < ey; ++y) {
            const float* row = b + y * WW;
            for (int x = sx; x < ex; ++x) acc += row[x];
        }
        sink += acc;
    }
    // sink == REPS * acc (up to ~2^-18 relative rounding); REPS is 2^6 so the
    // scale-back is exact in the exponent.
    out[idx] = sink * rcnt * (1.0f / (float)REPS);
}

extern "C" void kernel_launch(void* const* d_in, const int* in_sizes, int n_in,
                              void* d_out, int out_size, void* d_ws, size_t ws_size,
                              hipStream_t stream) {
    const float* input    = (const float*)d_in[0];
    const int*   size_raw = (const int*)d_in[1];
    const int*   pix      = (const int*)d_in[2];
    const int*   channels = (const int*)d_in[3];
    float*       out      = (float*)d_out;

    const int total = PP * SS * NC * OO * OO;   // 4,194,304
    probe_kernel<<<total / 256, 256, 0, stream>>>(input, size_raw, pix, channels, out);
}

// Round 9
// 38.341 us; speedup vs baseline: 47.3406x; 47.3406x over previous
//
#include <hip/hip_runtime.h>

// Problem constants (match reference)
#define PP 32
#define SS 4
#define CC 64
#define HH 128
#define WW 128
#define NC 32
#define OO 32
#define PLANE (HH * WW)
#define NTOT (PP * SS * CC * PLANE)   // 33,554,432 elements

// ws: int cbase[PP*NC]; int psize[PP]
// cbase[p*NC+c] = element offset of crop origin (incl. offy*W + offx) in
// the (p, s=0, channels[p][c]) plane.
__global__ __launch_bounds__(256) void setup_kernel(
    const int* __restrict__ size_raw,
    const int* __restrict__ pix,
    const int* __restrict__ channels,
    int*       __restrict__ cbase,   // [PP*NC]
    int*       __restrict__ psize)   // [PP]
{
    const int i = blockIdx.x * 256 + threadIdx.x;   // 0..1023
    const int p = i >> 5;
    const int c = i & 31;
    const int size = size_raw[p] + OO;              // [32,128]
    const int wr = WW - size + 1;
    const int hr = HH - size + 1;
    const int pm = pix[p] % (wr * hr);
    const int offy = pm / wr;
    const int offx = pm - offy * wr;
    if (c == 0) psize[p] = size;
    const int ch = channels[p * NC + c];
    cbase[i] = (p * SS * CC + ch) * PLANE + offy * WW + offx;
}

// One thread per output element; branch-free deep-MLP loads.
// Bin spans cols<=5 floats; the 16B-aligned 8-float window [a0, a0+8)
// always covers it (shift sh<=3). Always load 5 rows x 2 float4 (row index
// clamped -> duplicate rows are L1 hits; clamped tail stays in-bounds),
// reduce with precomputed masks (scale folded in). 10 independent 16B
// loads per thread, zero divergent branches around loads.
__global__ __launch_bounds__(256) void pool_kernel(
    const float* __restrict__ input,   // [P,S,C,H,W]
    const int*   __restrict__ cbase,   // [PP*NC]
    const int*   __restrict__ psize,   // [PP]
    float*       __restrict__ out)     // [P,S,NC,O,O]
{
    const int idx = blockIdx.x * 256 + threadIdx.x;
    const int q = idx & (OO - 1);
    const int o = (idx >> 5) & (OO - 1);
    const int c = (idx >> 10) & (NC - 1);
    const int s = (idx >> 15) & (SS - 1);
    const int p = idx >> 17;

    const int size = psize[p];                       // wave-uniform
    const int sy = (o * size) >> 5;
    const int rows = (((o + 1) * size + 31) >> 5) - sy;   // 1..5
    const int sx = (q * size) >> 5;
    const int cols = (((q + 1) * size + 31) >> 5) - sx;   // 1..5

    // absolute element offset of bin start; align to 16B
    const int abs0 = cbase[(p << 5) | c] + s * (CC * PLANE) + sy * WW + sx;
    const int sh = abs0 & 3;
    const int a0 = abs0 - sh;

    const float rscale = __builtin_amdgcn_rcpf((float)(rows * cols));

    // window masks with scale folded in: position j active iff (j-sh) in [0,cols)
    float m[8];
    #pragma unroll
    for (int j = 0; j < 8; ++j)
        m[j] = ((unsigned)(j - sh) < (unsigned)cols) ? rscale : 0.0f;

    float acc = 0.0f;
    #pragma unroll
    for (int dy = 0; dy < 5; ++dy) {
        const int yy = (dy < rows) ? dy : (rows - 1);   // clamp: dup rows L1-hit
        int ro = a0 + yy * WW;
        ro = (ro > NTOT - 8) ? (NTOT - 8) : ro;         // in-bounds, keeps alignment
        const float4 A = *(const float4*)(input + ro);
        const float4 B = *(const float4*)(input + ro + 4);
        float rsum = m[0] * A.x + m[1] * A.y + m[2] * A.z + m[3] * A.w
                   + m[4] * B.x + m[5] * B.y + m[6] * B.z + m[7] * B.w;
        if (dy > 0) rsum = (dy < rows) ? rsum : 0.0f;   // per-row validity
        acc += rsum;
    }
    out[idx] = acc;
}

extern "C" void kernel_launch(void* const* d_in, const int* in_sizes, int n_in,
                              void* d_out, int out_size, void* d_ws, size_t ws_size,
                              hipStream_t stream) {
    const float* input    = (const float*)d_in[0];
    const int*   size_raw = (const int*)d_in[1];
    const int*   pix      = (const int*)d_in[2];
    const int*   channels = (const int*)d_in[3];
    float*       out      = (float*)d_out;

    int* cbase = (int*)d_ws;            // 1024 ints
    int* psize = cbase + PP * NC;       // 32 ints

    setup_kernel<<<4, 256, 0, stream>>>(size_raw, pix, channels, cbase, psize);

    const int total = PP * SS * NC * OO * OO;   // 4,194,304
    pool_kernel<<<total / 256, 256, 0, stream>>>(input, cbase, psize, out);
}